// Round 3
// baseline (274.880 us; speedup 1.0000x reference)
//
#include <hip/hip_runtime.h>
#include <hip/hip_bf16.h>

typedef __attribute__((ext_vector_type(8))) short short8;
typedef __attribute__((ext_vector_type(4))) float f32x4;
typedef __attribute__((ext_vector_type(4))) unsigned int u32x4;
typedef unsigned long long u64;
typedef unsigned short u16;
typedef unsigned int u32;

#define NODES 512
#define HIDDEN 512
#define NEDGES 16384

// ---- helpers ----
static __device__ __forceinline__ u16 f2bf(float f) {
  unsigned u = __float_as_uint(f);
  u += 0x7FFFu + ((u >> 16) & 1u);
  return (u16)(u >> 16);
}

static __device__ __forceinline__ void gld_lds16(const void* g, void* l) {
  __builtin_amdgcn_global_load_lds(
      (const __attribute__((address_space(1))) unsigned int*)g,
      (__attribute__((address_space(3))) unsigned int*)l, 16, 0, 0);
}

// ---- kernel 1: fp32 -> bf16 cast (vectorized) ----
__global__ void cast_f32_bf16(const float* __restrict__ in, u16* __restrict__ out, int n4) {
  int stride = gridDim.x * blockDim.x;
  for (int i = blockIdx.x * blockDim.x + threadIdx.x; i < n4; i += stride) {
    float4 v = reinterpret_cast<const float4*>(in)[i];
    ushort4 o;
    o.x = f2bf(v.x); o.y = f2bf(v.y); o.z = f2bf(v.z); o.w = f2bf(v.w);
    reinterpret_cast<ushort4*>(out)[i] = o;
  }
}

// fused cast of the three 512x512 weight matrices
__global__ void cast_w3(const float* __restrict__ a, const float* __restrict__ b,
                        const float* __restrict__ c, u16* __restrict__ out) {
  int i = blockIdx.x * blockDim.x + threadIdx.x;  // 0..196607 (3*65536 float4s)
  const float* src = (i < 65536) ? a : (i < 131072) ? b : c;
  float4 v = reinterpret_cast<const float4*>(src)[i & 65535];
  ushort4 o;
  o.x = f2bf(v.x); o.y = f2bf(v.y); o.z = f2bf(v.z); o.w = f2bf(v.w);
  reinterpret_cast<ushort4*>(out)[i] = o;
}

// ---- kernel 2: adjacency bitmask scatter ----
__global__ void mask_scatter(const int* __restrict__ e, u64* __restrict__ bits) {
  int i = blockIdx.x * blockDim.x + threadIdx.x;
  if (i < NEDGES) {
    int src = e[i];
    int dst = e[NEDGES + i];
    atomicOr(&bits[src * 8 + (dst >> 6)], 1ull << (dst & 63));
  }
}

// ---- kernel 3: fused QKV GEMM ----
// M = 24576, N = 512, K = 512.  z in {0,1,2}.
// z=0,1: qkv[z][bh][node][d], computed with SWAPPED operands (A=W,B=x) so the
//        accumulator r-run spans d -> vectorized ushort4 stores.
// z=2:   TRANSPOSED vt[bh][d][node] (r-run spans node), ushort4 stores.
__global__ __launch_bounds__(256, 2)
void qkv_gemm(const u16* __restrict__ xb, const u16* __restrict__ wb,
              const float* __restrict__ bq, const float* __restrict__ bk,
              const float* __restrict__ bv, u16* __restrict__ qkv) {
  __shared__ u16 As[128 * 64];
  __shared__ u16 Bs[128 * 64];

  // XCD-aware 1D grid: each XCD owns a contiguous m-panel for all (n0,z)
  const int blk = blockIdx.x;
  const int xcd = blk & 7;
  const int i = blk >> 3;              // 0..287
  const int m0 = ((i % 24) + xcd * 24) * 128;
  const int nz = i / 24;               // 0..11
  const int n0 = (nz & 3) * 128;
  const int z = nz >> 2;

  const u16* Wz = wb + (size_t)z * (512 * 512);
  const float* bias = (z == 0) ? bq : (z == 1) ? bk : bv;

  const int tid = threadIdx.x;
  const int lane = tid & 63;
  const int w = tid >> 6;
  const int wr = w >> 1, wc = w & 1;
  const int l = lane & 15, j = lane >> 4;

  f32x4 acc[4][4] = {};

  for (int kt = 0; kt < 8; ++kt) {
    const int k0 = kt * 64;
#pragma unroll
    for (int t = 0; t < 4; ++t) {
      int c = w * 4 + t;
      int row = c * 8 + (lane >> 3);
      int kb = (lane & 7) * 16;
      gld_lds16((const char*)xb + ((size_t)(m0 + row) * 512 + k0) * 2 + kb,
                (char*)As + c * 1024);
      gld_lds16((const char*)Wz + ((size_t)(n0 + row) * 512 + k0) * 2 + kb,
                (char*)Bs + c * 1024);
    }
    __syncthreads();
#pragma unroll
    for (int kk = 0; kk < 2; ++kk) {
      short8 a[4], b[4];
      const int kf = kk * 32 + j * 8;
#pragma unroll
      for (int mi = 0; mi < 4; ++mi)
        a[mi] = *(const short8*)(As + (wr * 64 + mi * 16 + l) * 64 + kf);
#pragma unroll
      for (int ni = 0; ni < 4; ++ni)
        b[ni] = *(const short8*)(Bs + (wc * 64 + ni * 16 + l) * 64 + kf);
      if (z == 2) {
#pragma unroll
        for (int mi = 0; mi < 4; ++mi)
#pragma unroll
          for (int ni = 0; ni < 4; ++ni)
            acc[mi][ni] = __builtin_amdgcn_mfma_f32_16x16x32_bf16(a[mi], b[ni], acc[mi][ni], 0, 0, 0);
      } else {
#pragma unroll
        for (int mi = 0; mi < 4; ++mi)
#pragma unroll
          for (int ni = 0; ni < 4; ++ni)
            acc[mi][ni] = __builtin_amdgcn_mfma_f32_16x16x32_bf16(b[ni], a[mi], acc[mi][ni], 0, 0, 0);
      }
    }
    __syncthreads();
  }

  if (z == 2) {
    // C[row=m][col=n]: col = l -> n(d-col), rows r-run spans node
#pragma unroll
    for (int ni = 0; ni < 4; ++ni) {
      int jcol = n0 + wc * 64 + ni * 16 + l;
      float bv_ = bias[jcol];
      int h = jcol >> 6, d = jcol & 63;
#pragma unroll
      for (int mi = 0; mi < 4; ++mi) {
        int m = m0 + wr * 64 + mi * 16 + j * 4;
        int bs = m >> 9, node = m & 511;
        ushort4 pk;
#pragma unroll
        for (int r = 0; r < 4; ++r) pk[r] = f2bf(acc[mi][ni][r] + bv_);
        *reinterpret_cast<ushort4*>(qkv + (size_t)768 * 32768 +
            ((size_t)(bs * 8 + h) * 64 + d) * 512 + node) = pk;
      }
    }
  } else {
    // swapped: C[row=n][col=m]: col = l -> m(node), rows r-run spans d
#pragma unroll
    for (int ni = 0; ni < 4; ++ni) {
      int n_base = n0 + wc * 64 + ni * 16 + j * 4;
      float4 b4 = *reinterpret_cast<const float4*>(bias + n_base);
      int h = n_base >> 6, d0 = n_base & 63;
#pragma unroll
      for (int mi = 0; mi < 4; ++mi) {
        int m = m0 + wr * 64 + mi * 16 + l;
        int bs = m >> 9, node = m & 511;
        ushort4 pk;
#pragma unroll
        for (int r = 0; r < 4; ++r) pk[r] = f2bf(acc[mi][ni][r] + (&b4.x)[r]);
        *reinterpret_cast<ushort4*>(qkv + (size_t)(z * 384 + bs * 8 + h) * 32768 +
            node * 64 + d0) = pk;
      }
    }
  }
}

// ---- kernel 4: masked attention, NO LDS, NO barriers ----
// K/V are L1/L2-resident (128KB per bh shared by 8 co-XCD blocks) -> load
// MFMA fragments straight from global. Swapped QK^T; in-register P->bf16
// (cvt_pk) + permlane16/32_swap redistribution to the PV A-fragment.
__global__ __launch_bounds__(256, 4)
void attn_kernel(const u16* __restrict__ qkv, const u64* __restrict__ maskbits,
                 float* __restrict__ out) {
  const int blk = blockIdx.x;
  const int bh = (blk & 7) * 48 + (blk >> 6);
  const int qt = (blk >> 3) & 7;
  const int bs = bh >> 3, h = bh & 7;
  const int tid = threadIdx.x;
  const int lane = tid & 63;
  const int w = tid >> 6;
  const int l = lane & 15, j = lane >> 4;
  const int q0 = qt * 64;
  const int qrow = q0 + w * 16 + l;

  const u16* Qg  = qkv + (size_t)bh * 32768;
  const u16* Kg  = qkv + (size_t)(384 + bh) * 32768;   // [key][d]
  const u16* VTg = qkv + (size_t)(768 + bh) * 32768;   // [d][node]

  // Q fragments (B operand), held all kernel
  short8 qf[2];
#pragma unroll
  for (int kk = 0; kk < 2; ++kk)
    qf[kk] = *(const short8*)(Qg + qrow * 64 + kk * 32 + j * 8);

  // pre-pack this lane's mask bits: 16 bits per tile (key = ni*16 + j*4 + r)
  u32 mpack[4];
  {
    const u64* mrow = maskbits + qrow * 8;
#pragma unroll
    for (int t2 = 0; t2 < 4; ++t2) {
      u64 m0 = mrow[2 * t2], m1 = mrow[2 * t2 + 1];
      u32 a = 0, b = 0;
#pragma unroll
      for (int ni = 0; ni < 4; ++ni) {
        a |= ((u32)(m0 >> (ni * 16 + j * 4)) & 0xFu) << (ni * 4);
        b |= ((u32)(m1 >> (ni * 16 + j * 4)) & 0xFu) << (ni * 4);
      }
      mpack[t2] = a | (b << 16);
    }
  }

  f32x4 o[4] = {};
  float lsum = 0.0f;

  for (int kt = 0; kt < 8; ++kt) {
    const u16* Kt = Kg + kt * 4096;     // 64 keys x 64 d
    const u16* Vt = VTg + kt * 64;      // 64 d x 512 nodes, col offset kt*64

    // QK^T: A = K rows (key = ni*16+l), B = Q. C: col=l=q, row=key
    f32x4 st[4];
#pragma unroll
    for (int ni = 0; ni < 4; ++ni) {
      int key = ni * 16 + l;
      short8 ka0 = *(const short8*)(Kt + key * 64 + j * 8);
      short8 ka1 = *(const short8*)(Kt + key * 64 + 32 + j * 8);
      f32x4 zz = {};
      zz = __builtin_amdgcn_mfma_f32_16x16x32_bf16(ka0, qf[0], zz, 0, 0, 0);
      st[ni] = __builtin_amdgcn_mfma_f32_16x16x32_bf16(ka1, qf[1], zz, 0, 0, 0);
    }

    // P = mask ? exp2(s * log2e/8) : 0 ; pack bf16 pairs in-register
    u32 msk = (mpack[kt >> 1] >> ((kt & 1) * 16)) & 0xFFFFu;
    u32 p2[4][2];
#pragma unroll
    for (int ni = 0; ni < 4; ++ni) {
      float pr[4];
#pragma unroll
      for (int r = 0; r < 4; ++r) {
        float e = __builtin_exp2f(st[ni][r] * 0.18033688f);
        pr[r] = ((msk >> (ni * 4 + r)) & 1u) ? e : 0.0f;
        lsum += pr[r];
      }
      asm("v_cvt_pk_bf16_f32 %0, %1, %2" : "=v"(p2[ni][0]) : "v"(pr[0]), "v"(pr[1]));
      asm("v_cvt_pk_bf16_f32 %0, %1, %2" : "=v"(p2[ni][1]) : "v"(pr[2]), "v"(pr[3]));
    }

    // redistribute to PV A-frag via permlane swaps (replaces 16 bpermutes):
    // target lane (j,l) word w2=2t+s <- p2[2kk + (j>>1)][s] @ row j'=2(j&1)+t
    u32x4 paw[2];
#pragma unroll
    for (int kk = 0; kk < 2; ++kk) {
      u32 X0 = p2[2 * kk][0], X1 = p2[2 * kk][1];
      u32 Y0 = p2[2 * kk + 1][0], Y1 = p2[2 * kk + 1][1];
      asm("v_permlane32_swap_b32 %0, %1" : "+v"(X0), "+v"(Y0));  // X0=[X0lo,Y0lo] Y0=[X0hi,Y0hi]
      asm("v_permlane32_swap_b32 %0, %1" : "+v"(X1), "+v"(Y1));
      asm("v_permlane16_swap_b32 %0, %1" : "+v"(X0), "+v"(Y0));  // X0=[X0r0,Y0'..] -> paw0, Y0 -> paw2
      asm("v_permlane16_swap_b32 %0, %1" : "+v"(X1), "+v"(Y1));
      paw[kk][0] = X0; paw[kk][1] = X1; paw[kk][2] = Y0; paw[kk][3] = Y1;
    }

    // O += P V : A = P (q rows), B = V^T rows (d), contraction over keys
#pragma unroll
    for (int ni = 0; ni < 4; ++ni) {
      int d = ni * 16 + l;
      short8 vb0 = *(const short8*)(Vt + d * 512 + j * 8);
      short8 vb1 = *(const short8*)(Vt + d * 512 + 32 + j * 8);
      o[ni] = __builtin_amdgcn_mfma_f32_16x16x32_bf16(__builtin_bit_cast(short8, paw[0]), vb0, o[ni], 0, 0, 0);
      o[ni] = __builtin_amdgcn_mfma_f32_16x16x32_bf16(__builtin_bit_cast(short8, paw[1]), vb1, o[ni], 0, 0, 0);
    }
  }

  // softmax denominator: reduce over j-copies of this q column
  float tsum = lsum + __shfl_xor(lsum, 16);
  tsum += __shfl_xor(tsum, 32);
  float inv = 1.0f / tsum;
  float invr[4];
#pragma unroll
  for (int r = 0; r < 4; ++r) invr[r] = __shfl(inv, j * 4 + r);

#pragma unroll
  for (int ni = 0; ni < 4; ++ni) {
    int d = ni * 16 + l;
#pragma unroll
    for (int r = 0; r < 4; ++r) {
      int node = q0 + w * 16 + j * 4 + r;
      out[(size_t)bs * 262144 + (size_t)node * 512 + h * 64 + d] = o[ni][r] * invr[r];
    }
  }
}

// ---- launcher ----
extern "C" void kernel_launch(void* const* d_in, const int* in_sizes, int n_in,
                              void* d_out, int out_size, void* d_ws, size_t ws_size,
                              hipStream_t stream) {
  const float* x  = (const float*)d_in[0];
  const int*   e  = (const int*)d_in[1];
  const float* Wq = (const float*)d_in[2];
  const float* bq = (const float*)d_in[3];
  const float* Wk = (const float*)d_in[4];
  const float* bk = (const float*)d_in[5];
  const float* Wv = (const float*)d_in[6];
  const float* bv = (const float*)d_in[7];
  float* out = (float*)d_out;

  char* ws = (char*)d_ws;
  u16* xb   = (u16*)(ws);                 // 24576*512 bf16 = 25165824 B
  u16* wb   = (u16*)(ws + 25165824);      // 3*512*512 bf16 = 1572864 B
  u16* qkv  = (u16*)(ws + 26738688);      // 3*384*512*64 bf16 = 75497472 B
  u64* mb   = (u64*)(ws + 102236160);     // 512*8 u64 = 32768 B

  hipMemsetAsync(mb, 0, 512 * 8 * sizeof(u64), stream);
  mask_scatter<<<(NEDGES + 255) / 256, 256, 0, stream>>>(e, mb);

  cast_f32_bf16<<<2048, 256, 0, stream>>>(x, xb, (24576 * 512) / 4);
  cast_w3<<<768, 256, 0, stream>>>(Wq, Wk, Wv, wb);

  qkv_gemm<<<2304, 256, 0, stream>>>(xb, wb, bq, bk, bv, qkv);
  attn_kernel<<<48 * 8 * 8, 256, 0, stream>>>(qkv, mb, out);
}

// Round 4
// 151.735 us; speedup vs baseline: 1.8116x; 1.8116x over previous
//
#include <hip/hip_runtime.h>
#include <hip/hip_bf16.h>

typedef __attribute__((ext_vector_type(8))) short short8;
typedef __attribute__((ext_vector_type(4))) float f32x4;
typedef __attribute__((ext_vector_type(4))) unsigned int u32x4;
typedef unsigned long long u64;
typedef unsigned short u16;
typedef unsigned int u32;

#define NODES 512
#define HIDDEN 512
#define NEDGES 16384

// qkv fragment regions (u16 offsets)
#define KOFF ((size_t)384 * 32 * 2 * 512)          // 12582912
#define VOFF ((size_t)2 * 384 * 32 * 2 * 512)      // 25165824

// ---- helpers ----
static __device__ __forceinline__ u16 f2bf(float f) {
  unsigned u = __float_as_uint(f);
  u += 0x7FFFu + ((u >> 16) & 1u);
  return (u16)(u >> 16);
}

static __device__ __forceinline__ void gld_lds16(const void* g, void* l) {
  __builtin_amdgcn_global_load_lds(
      (const __attribute__((address_space(1))) unsigned int*)g,
      (__attribute__((address_space(3))) unsigned int*)l, 16, 0, 0);
}

// ---- kernel 1: fp32 -> bf16 cast (vectorized) ----
__global__ void cast_f32_bf16(const float* __restrict__ in, u16* __restrict__ out, int n4) {
  int stride = gridDim.x * blockDim.x;
  for (int i = blockIdx.x * blockDim.x + threadIdx.x; i < n4; i += stride) {
    float4 v = reinterpret_cast<const float4*>(in)[i];
    ushort4 o;
    o.x = f2bf(v.x); o.y = f2bf(v.y); o.z = f2bf(v.z); o.w = f2bf(v.w);
    reinterpret_cast<ushort4*>(out)[i] = o;
  }
}

// fused cast of the three 512x512 weight matrices
__global__ void cast_w3(const float* __restrict__ a, const float* __restrict__ b,
                        const float* __restrict__ c, u16* __restrict__ out) {
  int i = blockIdx.x * blockDim.x + threadIdx.x;
  const float* src = (i < 65536) ? a : (i < 131072) ? b : c;
  float4 v = reinterpret_cast<const float4*>(src)[i & 65535];
  ushort4 o;
  o.x = f2bf(v.x); o.y = f2bf(v.y); o.z = f2bf(v.z); o.w = f2bf(v.w);
  reinterpret_cast<ushort4*>(out)[i] = o;
}

// ---- kernel 2: adjacency bitmask scatter ----
__global__ void mask_scatter(const int* __restrict__ e, u64* __restrict__ bits) {
  int i = blockIdx.x * blockDim.x + threadIdx.x;
  if (i < NEDGES) {
    int src = e[i];
    int dst = e[NEDGES + i];
    atomicOr(&bits[src * 8 + (dst >> 6)], 1ull << (dst & 63));
  }
}

// ---- kernel 3: fused QKV GEMM with FRAGMENT-LAYOUT epilogues ----
// M = 24576, N = 512, K = 512. z in {0,1,2}.
// Q frags: [bh][qsg 0..31][kk 0..1][64 lanes x 8 u16]   (granule: q=qsg*16+l, d=kk*32+oct*8+e)
// K frags: [bh][kt 0..7][ks 0..3][kk][64 lanes x 8]     (key=kt*64+ks*16+l, d=kk*32+oct*8+e)
// V frags: [bh][kt][kk2 0..1][ds 0..3][64 lanes x 8]    (d=ds*16+l, key=kt*64+kk2*32+oct*8+e)
__global__ __launch_bounds__(256, 2)
void qkv_gemm(const u16* __restrict__ xb, const u16* __restrict__ wb,
              const float* __restrict__ bq, const float* __restrict__ bk,
              const float* __restrict__ bv, u16* __restrict__ qkv) {
  __shared__ u16 As[128 * 64];
  __shared__ u16 Bs[128 * 64];

  const int blk = blockIdx.x;
  const int xcd = blk & 7;
  const int i = blk >> 3;
  const int m0 = ((i % 24) + xcd * 24) * 128;
  const int nz = i / 24;
  const int n0 = (nz & 3) * 128;
  const int z = nz >> 2;

  const u16* Wz = wb + (size_t)z * (512 * 512);
  const float* bias = (z == 0) ? bq : (z == 1) ? bk : bv;

  const int tid = threadIdx.x;
  const int lane = tid & 63;
  const int w = tid >> 6;
  const int wr = w >> 1, wc = w & 1;
  const int l = lane & 15, j = lane >> 4;

  f32x4 acc[4][4] = {};

  for (int kt = 0; kt < 8; ++kt) {
    const int k0 = kt * 64;
#pragma unroll
    for (int t = 0; t < 4; ++t) {
      int c = w * 4 + t;
      int row = c * 8 + (lane >> 3);
      int kb = (lane & 7) * 16;
      gld_lds16((const char*)xb + ((size_t)(m0 + row) * 512 + k0) * 2 + kb,
                (char*)As + c * 1024);
      gld_lds16((const char*)Wz + ((size_t)(n0 + row) * 512 + k0) * 2 + kb,
                (char*)Bs + c * 1024);
    }
    __syncthreads();
#pragma unroll
    for (int kk = 0; kk < 2; ++kk) {
      short8 a[4], b[4];
      const int kf = kk * 32 + j * 8;
#pragma unroll
      for (int mi = 0; mi < 4; ++mi)
        a[mi] = *(const short8*)(As + (wr * 64 + mi * 16 + l) * 64 + kf);
#pragma unroll
      for (int ni = 0; ni < 4; ++ni)
        b[ni] = *(const short8*)(Bs + (wc * 64 + ni * 16 + l) * 64 + kf);
      if (z == 2) {
#pragma unroll
        for (int mi = 0; mi < 4; ++mi)
#pragma unroll
          for (int ni = 0; ni < 4; ++ni)
            acc[mi][ni] = __builtin_amdgcn_mfma_f32_16x16x32_bf16(a[mi], b[ni], acc[mi][ni], 0, 0, 0);
      } else {
#pragma unroll
        for (int mi = 0; mi < 4; ++mi)
#pragma unroll
          for (int ni = 0; ni < 4; ++ni)
            acc[mi][ni] = __builtin_amdgcn_mfma_f32_16x16x32_bf16(b[ni], a[mi], acc[mi][ni], 0, 0, 0);
      }
    }
    __syncthreads();
  }

  const int bs = m0 >> 9;
  const int hh = (n0 >> 6) + wc;
  const int bh = bs * 8 + hh;

  if (z == 2) {
    // unswapped: col l -> d (dd = ni*16+l), rows j*4+r -> key
    const int ktb = ((m0 & 511) >> 6) + wr;
#pragma unroll
    for (int ni = 0; ni < 4; ++ni) {
      int jcol = n0 + wc * 64 + ni * 16 + l;
      float bv_ = bias[jcol];
      int ds = ni;
#pragma unroll
      for (int mi = 0; mi < 4; ++mi) {
        int kk2 = mi >> 1, oct = ((mi & 1) << 1) | (j >> 1);
        ushort4 pk;
#pragma unroll
        for (int r = 0; r < 4; ++r) pk[r] = f2bf(acc[mi][ni][r] + bv_);
        size_t idx = VOFF + (((((size_t)bh * 8 + ktb) * 2 + kk2) * 4 + ds) * 512)
                   + (oct * 16 + l) * 8 + (j & 1) * 4;
        *reinterpret_cast<ushort4*>(qkv + idx) = pk;
      }
    }
  } else {
    // swapped: rows j*4+r -> d (dd = ni*16+j*4+r), col l -> node
#pragma unroll
    for (int ni = 0; ni < 4; ++ni) {
      int n_base = n0 + wc * 64 + ni * 16 + j * 4;
      float4 b4 = *reinterpret_cast<const float4*>(bias + n_base);
      int kk = ni >> 1, oct = ((ni & 1) << 1) | (j >> 1);
#pragma unroll
      for (int mi = 0; mi < 4; ++mi) {
        ushort4 pk;
#pragma unroll
        for (int r = 0; r < 4; ++r) pk[r] = f2bf(acc[mi][ni][r] + (&b4.x)[r]);
        size_t idx;
        if (z == 0) {
          int qsg = ((m0 & 511) >> 4) + wr * 4 + mi;
          idx = ((((size_t)bh * 32 + qsg) * 2 + kk) * 512) + (oct * 16 + l) * 8 + (j & 1) * 4;
        } else {
          int ktb = ((m0 & 511) >> 6) + wr;
          idx = KOFF + (((((size_t)bh * 8 + ktb) * 4 + mi) * 2 + kk) * 512)
              + (oct * 16 + l) * 8 + (j & 1) * 4;
        }
        *reinterpret_cast<ushort4*>(qkv + idx) = pk;
      }
    }
  }
}

// ---- kernel 4: masked attention — fragment-direct, no LDS, no barriers ----
// Block = (bh, qhalf): 4 waves x 64 q-rows. All frag loads are contiguous
// 1KB coalesced dwordx4. Swapped QK^T; in-register P (cvt_pk + permlane);
// row-sums via P x ones MFMA (lands in o's lane layout -> no shuffles).
__global__ __launch_bounds__(256, 2)
void attn_kernel(const u16* __restrict__ qkv, const u64* __restrict__ maskbits,
                 float* __restrict__ out) {
  const int blk = blockIdx.x;
  const int xcd = blk & 7;
  const int i = blk >> 3;                 // 0..95
  const int bh = xcd * 48 + (i >> 1);
  const int qhalf = i & 1;
  const int bs = bh >> 3, h = bh & 7;
  const int tid = threadIdx.x;
  const int lane = tid & 63;
  const int w = tid >> 6;
  const int l = lane & 15, j = lane >> 4;
  const int qb = qhalf * 16 + w * 4;      // qsg base (4 subtiles per wave)

  const u16* Qf = qkv;
  const u16* Kf = qkv + KOFF;
  const u16* Vf = qkv + VOFF;

  // Q fragments, held all kernel
  short8 qf[4][2];
#pragma unroll
  for (int qs = 0; qs < 4; ++qs)
#pragma unroll
    for (int kk = 0; kk < 2; ++kk)
      qf[qs][kk] = *(const short8*)(Qf + (((size_t)bh * 32 + qb + qs) * 2 + kk) * 512 + lane * 8);

  // mask prepack: mreg[kt*2+hh] bit (qs*8 + lks*4 + r) = edge(q, key)
  // q = (qb+qs)*16 + l ; key = kt*64 + hh*32 + lks*16 + j*4 + r
  u32 mreg[16];
#pragma unroll
  for (int t = 0; t < 16; ++t) mreg[t] = 0;
#pragma unroll
  for (int qs = 0; qs < 4; ++qs) {
    const u64* mrow = maskbits + ((size_t)((qb + qs) * 16 + l)) * 8;
#pragma unroll
    for (int kt = 0; kt < 8; ++kt) {
      u64 mw = mrow[kt];
#pragma unroll
      for (int hh = 0; hh < 2; ++hh)
#pragma unroll
        for (int lks = 0; lks < 2; ++lks)
          mreg[kt * 2 + hh] |= ((u32)(mw >> (hh * 32 + lks * 16 + j * 4)) & 0xFu)
                               << (qs * 8 + lks * 4);
    }
  }

  f32x4 o[4][4] = {};
  f32x4 osum[4] = {};
  short8 ones;
#pragma unroll
  for (int t = 0; t < 8; ++t) ones[t] = (short)0x3F80;  // bf16 1.0

#pragma unroll 2
  for (int kt = 0; kt < 8; ++kt) {
#pragma unroll
    for (int hh = 0; hh < 2; ++hh) {
      // K fragments for this 32-key half (2 ks-subtiles x 2 kk)
      short8 kf2[2][2];
#pragma unroll
      for (int lks = 0; lks < 2; ++lks)
#pragma unroll
        for (int kk = 0; kk < 2; ++kk)
          kf2[lks][kk] = *(const short8*)(Kf +
              ((((size_t)bh * 8 + kt) * 4 + hh * 2 + lks) * 2 + kk) * 512 + lane * 8);
      // V fragments (4 d-subtiles, this key-half)
      short8 vf[4];
#pragma unroll
      for (int ds = 0; ds < 4; ++ds)
        vf[ds] = *(const short8*)(Vf +
            ((((size_t)bh * 8 + kt) * 2 + hh) * 4 + ds) * 512 + lane * 8);

      // QK^T: st[qs][lks], col l = q, row j*4+r = key-in-16
      f32x4 st[4][2] = {};
#pragma unroll
      for (int qs = 0; qs < 4; ++qs)
#pragma unroll
        for (int lks = 0; lks < 2; ++lks)
#pragma unroll
          for (int kk = 0; kk < 2; ++kk)
            st[qs][lks] = __builtin_amdgcn_mfma_f32_16x16x32_bf16(
                kf2[lks][kk], qf[qs][kk], st[qs][lks], 0, 0, 0);

      const u32 m32 = mreg[kt * 2 + hh];
#pragma unroll
      for (int qs = 0; qs < 4; ++qs) {
        float pr[8];
#pragma unroll
        for (int lks = 0; lks < 2; ++lks)
#pragma unroll
          for (int r = 0; r < 4; ++r) {
            float e = __builtin_exp2f(st[qs][lks][r] * 0.18033688f);
            pr[lks * 4 + r] = ((m32 >> (qs * 8 + lks * 4 + r)) & 1u) ? e : 0.0f;
          }
        u32 X0, X1, Y0, Y1;
        asm("v_cvt_pk_bf16_f32 %0, %1, %2" : "=v"(X0) : "v"(pr[0]), "v"(pr[1]));
        asm("v_cvt_pk_bf16_f32 %0, %1, %2" : "=v"(X1) : "v"(pr[2]), "v"(pr[3]));
        asm("v_cvt_pk_bf16_f32 %0, %1, %2" : "=v"(Y0) : "v"(pr[4]), "v"(pr[5]));
        asm("v_cvt_pk_bf16_f32 %0, %1, %2" : "=v"(Y1) : "v"(pr[6]), "v"(pr[7]));
        asm("v_permlane32_swap_b32 %0, %1" : "+v"(X0), "+v"(Y0));
        asm("v_permlane32_swap_b32 %0, %1" : "+v"(X1), "+v"(Y1));
        asm("v_permlane16_swap_b32 %0, %1" : "+v"(X0), "+v"(Y0));
        asm("v_permlane16_swap_b32 %0, %1" : "+v"(X1), "+v"(Y1));
        u32x4 paw = {X0, X1, Y0, Y1};
        short8 pa = __builtin_bit_cast(short8, paw);
        // row-sum on the MFMA pipe (same C layout as o)
        osum[qs] = __builtin_amdgcn_mfma_f32_16x16x32_bf16(pa, ones, osum[qs], 0, 0, 0);
#pragma unroll
        for (int ds = 0; ds < 4; ++ds)
          o[qs][ds] = __builtin_amdgcn_mfma_f32_16x16x32_bf16(pa, vf[ds], o[qs][ds], 0, 0, 0);
      }
    }
  }

  // epilogue: normalize (osum already in o's lane layout) and store
#pragma unroll
  for (int qs = 0; qs < 4; ++qs) {
    f32x4 inv4;
#pragma unroll
    for (int r = 0; r < 4; ++r) inv4[r] = 1.0f / osum[qs][r];
#pragma unroll
    for (int ds = 0; ds < 4; ++ds) {
      int d = ds * 16 + l;
#pragma unroll
      for (int r = 0; r < 4; ++r) {
        int node = (qb + qs) * 16 + j * 4 + r;
        out[(size_t)bs * 262144 + (size_t)node * 512 + h * 64 + d] = o[qs][ds][r] * inv4[r];
      }
    }
  }
}

// ---- launcher ----
extern "C" void kernel_launch(void* const* d_in, const int* in_sizes, int n_in,
                              void* d_out, int out_size, void* d_ws, size_t ws_size,
                              hipStream_t stream) {
  const float* x  = (const float*)d_in[0];
  const int*   e  = (const int*)d_in[1];
  const float* Wq = (const float*)d_in[2];
  const float* bq = (const float*)d_in[3];
  const float* Wk = (const float*)d_in[4];
  const float* bk = (const float*)d_in[5];
  const float* Wv = (const float*)d_in[6];
  const float* bv = (const float*)d_in[7];
  float* out = (float*)d_out;

  char* ws = (char*)d_ws;
  u16* xb   = (u16*)(ws);                 // 24576*512 bf16 = 25165824 B
  u16* wb   = (u16*)(ws + 25165824);      // 3*512*512 bf16 = 1572864 B
  u16* qkv  = (u16*)(ws + 26738688);      // 3*384*512*64 bf16 = 75497472 B
  u64* mb   = (u64*)(ws + 102236160);     // 512*8 u64 = 32768 B

  hipMemsetAsync(mb, 0, 512 * 8 * sizeof(u64), stream);
  mask_scatter<<<(NEDGES + 255) / 256, 256, 0, stream>>>(e, mb);

  cast_f32_bf16<<<2048, 256, 0, stream>>>(x, xb, (24576 * 512) / 4);
  cast_w3<<<768, 256, 0, stream>>>(Wq, Wk, Wv, wb);

  qkv_gemm<<<2304, 256, 0, stream>>>(xb, wb, bq, bk, bv, qkv);
  attn_kernel<<<768, 256, 0, stream>>>(qkv, mb, out);
}